// Round 1
// baseline (952.909 us; speedup 1.0000x reference)
//
#include <hip/hip_runtime.h>
#include <math.h>

#define DIM 1024
#define NUM_F 16
#define BATCH 4
#define SEQ 2048
#define NTOK (BATCH * SEQ)      // 8192
#define JCOLS 1088              // 1024 v | 16 kan_q | 16 kan_k | 32 zero pad
#define KAN_OFF 1024

// workspace layout (floats)
#define WCAT_FLOATS (JCOLS * DIM)          // 1,114,112
#define BCAT_OFF    WCAT_FLOATS
#define Y_OFF       (BCAT_OFF + JCOLS)     // 1,115,200
// total = Y_OFF + NTOK*JCOLS = 10,028,096 floats ~= 40.1 MB

// ---------------------------------------------------------------------------
// K1: Wcat[1024 + w*16 + f][d] += sum_e basis[f][e] * W_w[e][d]
// grid (2, DIM/256, 8 e-chunks), block 256. Accumulates atomically into the
// pre-zeroed kan rows of Wcat.
// ---------------------------------------------------------------------------
__global__ __launch_bounds__(256) void k_basisW(
    const float* __restrict__ basis, const float* __restrict__ Wq,
    const float* __restrict__ Wk, float* __restrict__ Wcat) {
  const int w = blockIdx.x;                       // 0 = q, 1 = k
  const int d = blockIdx.y * 256 + threadIdx.x;
  const int e0 = blockIdx.z * 128;
  const float* __restrict__ W = w ? Wk : Wq;
  float acc[NUM_F];
#pragma unroll
  for (int f = 0; f < NUM_F; ++f) acc[f] = 0.f;
#pragma unroll 4
  for (int e = e0; e < e0 + 128; ++e) {
    float wv = W[e * DIM + d];
#pragma unroll
    for (int f = 0; f < NUM_F; ++f)
      acc[f] = fmaf(basis[f * DIM + e], wv, acc[f]);
  }
#pragma unroll
  for (int f = 0; f < NUM_F; ++f)
    atomicAdd(&Wcat[(size_t)(KAN_OFF + w * NUM_F + f) * DIM + d], acc[f]);
}

// ---------------------------------------------------------------------------
// K1b: bcat[1024 + w*16 + f] = sum_e basis[f][e] * b_w[e]
// grid (32), block 64 (one wave).
// ---------------------------------------------------------------------------
__global__ void k_basisB(const float* __restrict__ basis,
                         const float* __restrict__ bq,
                         const float* __restrict__ bk,
                         float* __restrict__ bcat) {
  const int w = blockIdx.x >> 4, f = blockIdx.x & 15;
  const float* __restrict__ bb = w ? bk : bq;
  const int lane = threadIdx.x;
  float acc = 0.f;
#pragma unroll
  for (int j = 0; j < DIM / 64; ++j) {
    int e = lane + 64 * j;
    acc = fmaf(basis[f * DIM + e], bb[e], acc);
  }
#pragma unroll
  for (int off = 32; off; off >>= 1) acc += __shfl_down(acc, off, 64);
  if (lane == 0) bcat[KAN_OFF + w * NUM_F + f] = acc;
}

// ---------------------------------------------------------------------------
// K2: Y[n][j] = sum_e x[n][e] * Wcat[j][e] + bcat[j]   (NT GEMM, fp32 VALU)
// 64x64 tile, BK=16, 256 threads, 4x4 micro-tile.
// grid (JCOLS/64 = 17, NTOK/64 = 128)
// ---------------------------------------------------------------------------
#define BM 64
#define BN 64
#define BK 16
#define LDT 68  // +4 pad: breaks bank conflicts, keeps 16B row alignment

__global__ __launch_bounds__(256) void k_gemm(
    const float* __restrict__ A, const float* __restrict__ Wc,
    const float* __restrict__ bc, float* __restrict__ Y) {
  __shared__ float As[BK][LDT];
  __shared__ float Bs[BK][LDT];
  const int jb = blockIdx.x, nb = blockIdx.y;
  const int tid = threadIdx.x;
  const int rt = tid >> 4, ct = tid & 15;   // 16x16 thread grid, 4x4 each
  const int lr = tid >> 2;                  // load row 0..63
  const int lc = (tid & 3) << 2;            // load col 0,4,8,12
  float acc[4][4] = {{0.f}};
  const float* __restrict__ Ab = A + (size_t)(nb * BM + lr) * DIM + lc;
  const float* __restrict__ Bb = Wc + (size_t)(jb * BN + lr) * DIM + lc;

  for (int k0 = 0; k0 < DIM; k0 += BK) {
    float4 av = *(const float4*)(Ab + k0);
    float4 bv = *(const float4*)(Bb + k0);
    __syncthreads();
    As[lc + 0][lr] = av.x; As[lc + 1][lr] = av.y;
    As[lc + 2][lr] = av.z; As[lc + 3][lr] = av.w;
    Bs[lc + 0][lr] = bv.x; Bs[lc + 1][lr] = bv.y;
    Bs[lc + 2][lr] = bv.z; Bs[lc + 3][lr] = bv.w;
    __syncthreads();
#pragma unroll
    for (int kk = 0; kk < BK; ++kk) {
      float4 a = *(const float4*)&As[kk][rt * 4];
      float4 b = *(const float4*)&Bs[kk][ct * 4];
      acc[0][0] = fmaf(a.x, b.x, acc[0][0]);
      acc[0][1] = fmaf(a.x, b.y, acc[0][1]);
      acc[0][2] = fmaf(a.x, b.z, acc[0][2]);
      acc[0][3] = fmaf(a.x, b.w, acc[0][3]);
      acc[1][0] = fmaf(a.y, b.x, acc[1][0]);
      acc[1][1] = fmaf(a.y, b.y, acc[1][1]);
      acc[1][2] = fmaf(a.y, b.z, acc[1][2]);
      acc[1][3] = fmaf(a.y, b.w, acc[1][3]);
      acc[2][0] = fmaf(a.z, b.x, acc[2][0]);
      acc[2][1] = fmaf(a.z, b.y, acc[2][1]);
      acc[2][2] = fmaf(a.z, b.z, acc[2][2]);
      acc[2][3] = fmaf(a.z, b.w, acc[2][3]);
      acc[3][0] = fmaf(a.w, b.x, acc[3][0]);
      acc[3][1] = fmaf(a.w, b.y, acc[3][1]);
      acc[3][2] = fmaf(a.w, b.z, acc[3][2]);
      acc[3][3] = fmaf(a.w, b.w, acc[3][3]);
    }
  }
  const int j = jb * BN + ct * 4;
  float4 bb = *(const float4*)(bc + j);
#pragma unroll
  for (int i = 0; i < 4; ++i) {
    const int n = nb * BM + rt * 4 + i;
    float4 o;
    o.x = acc[i][0] + bb.x; o.y = acc[i][1] + bb.y;
    o.z = acc[i][2] + bb.z; o.w = acc[i][3] + bb.w;
    *(float4*)(Y + (size_t)n * JCOLS + j) = o;
  }
}

// ---------------------------------------------------------------------------
// K3: attention. Block = 16 query rows of one batch; 256 threads.
// Two-pass softmax (scores are 16-dots — recompute is cheap), then PV with
// thread-owned (16 q x 4 d) accumulators.
// grid (SEQ/16 = 128, BATCH = 4)
// ---------------------------------------------------------------------------
#define TQ 16
#define TM 256
#define LKK 20   // kk_s row stride: 2-way-max conflicts, 16B aligned
#define SPS 260  // ps row stride: 16B aligned (260*4 % 16 == 0)

__global__ __launch_bounds__(256) void k_attn(const float* __restrict__ Y,
                                              float* __restrict__ out) {
  __shared__ float kk_s[TM][LKK];
  __shared__ float ps[TQ][SPS];
  __shared__ float kq_s[TQ][16];
  __shared__ float red_m[TQ][16];
  __shared__ float red_l[TQ][16];
  __shared__ float smax[TQ];
  __shared__ float sinv[TQ];

  const int b = blockIdx.y;
  const int q0 = blockIdx.x * TQ;
  const int nbase = b * SEQ;
  const int tid = threadIdx.x;
  const int q = tid >> 4, t = tid & 15;
  const float scale = 0.03125f;  // 1/sqrt(1024)

  // stage kan_q tile
  kq_s[tid >> 4][tid & 15] =
      Y[(size_t)(nbase + q0 + (tid >> 4)) * JCOLS + KAN_OFF + (tid & 15)];
  __syncthreads();
  const float4 kq0 = *(const float4*)&kq_s[q][0];
  const float4 kq1 = *(const float4*)&kq_s[q][4];
  const float4 kq2 = *(const float4*)&kq_s[q][8];
  const float4 kq3 = *(const float4*)&kq_s[q][12];

  // ---- pass A: per-thread online (max, sumexp) over its 128 m's ----
  float m_run = -1e30f, l_run = 0.f;
  for (int m0 = 0; m0 < SEQ; m0 += TM) {
    __syncthreads();
#pragma unroll
    for (int i = 0; i < 16; ++i) {
      int idx = tid + 256 * i;
      int row = idx >> 4, f = idx & 15;
      kk_s[row][f] =
          Y[(size_t)(nbase + m0 + row) * JCOLS + KAN_OFF + 16 + f];
    }
    __syncthreads();
#pragma unroll
    for (int j = 0; j < 16; ++j) {
      const int mm = t + 16 * j;
      const float* kr = &kk_s[mm][0];
      float4 b0 = *(const float4*)(kr + 0);
      float4 b1 = *(const float4*)(kr + 4);
      float4 b2 = *(const float4*)(kr + 8);
      float4 b3 = *(const float4*)(kr + 12);
      float s = kq0.x * b0.x;
      s = fmaf(kq0.y, b0.y, s); s = fmaf(kq0.z, b0.z, s);
      s = fmaf(kq0.w, b0.w, s); s = fmaf(kq1.x, b1.x, s);
      s = fmaf(kq1.y, b1.y, s); s = fmaf(kq1.z, b1.z, s);
      s = fmaf(kq1.w, b1.w, s); s = fmaf(kq2.x, b2.x, s);
      s = fmaf(kq2.y, b2.y, s); s = fmaf(kq2.z, b2.z, s);
      s = fmaf(kq2.w, b2.w, s); s = fmaf(kq3.x, b3.x, s);
      s = fmaf(kq3.y, b3.y, s); s = fmaf(kq3.z, b3.z, s);
      s = fmaf(kq3.w, b3.w, s);
      s *= scale;
      float nm = fmaxf(m_run, s);
      l_run = l_run * __expf(m_run - nm) + __expf(s - nm);
      m_run = nm;
    }
  }
  red_m[q][t] = m_run;
  red_l[q][t] = l_run;
  __syncthreads();
  if (tid < TQ) {
    float mf = -1e30f;
#pragma unroll
    for (int i = 0; i < 16; ++i) mf = fmaxf(mf, red_m[tid][i]);
    float lf = 0.f;
#pragma unroll
    for (int i = 0; i < 16; ++i)
      lf += red_l[tid][i] * __expf(red_m[tid][i] - mf);
    smax[tid] = mf;
    sinv[tid] = 1.f / lf;
  }
  __syncthreads();
  const float mfq = smax[q];
  const float ilq = sinv[q];

  // ---- pass B: p into LDS, PV accumulate ----
  float4 acc[TQ];
#pragma unroll
  for (int i = 0; i < TQ; ++i) acc[i] = make_float4(0.f, 0.f, 0.f, 0.f);

  const float* __restrict__ vb0 = Y + (size_t)nbase * JCOLS + tid * 4;

  for (int m0 = 0; m0 < SEQ; m0 += TM) {
    __syncthreads();
#pragma unroll
    for (int i = 0; i < 16; ++i) {
      int idx = tid + 256 * i;
      int row = idx >> 4, f = idx & 15;
      kk_s[row][f] =
          Y[(size_t)(nbase + m0 + row) * JCOLS + KAN_OFF + 16 + f];
    }
    __syncthreads();
#pragma unroll
    for (int j = 0; j < 16; ++j) {
      const int mm = t + 16 * j;
      const float* kr = &kk_s[mm][0];
      float4 b0 = *(const float4*)(kr + 0);
      float4 b1 = *(const float4*)(kr + 4);
      float4 b2 = *(const float4*)(kr + 8);
      float4 b3 = *(const float4*)(kr + 12);
      float s = kq0.x * b0.x;
      s = fmaf(kq0.y, b0.y, s); s = fmaf(kq0.z, b0.z, s);
      s = fmaf(kq0.w, b0.w, s); s = fmaf(kq1.x, b1.x, s);
      s = fmaf(kq1.y, b1.y, s); s = fmaf(kq1.z, b1.z, s);
      s = fmaf(kq1.w, b1.w, s); s = fmaf(kq2.x, b2.x, s);
      s = fmaf(kq2.y, b2.y, s); s = fmaf(kq2.z, b2.z, s);
      s = fmaf(kq2.w, b2.w, s); s = fmaf(kq3.x, b3.x, s);
      s = fmaf(kq3.y, b3.y, s); s = fmaf(kq3.z, b3.z, s);
      s = fmaf(kq3.w, b3.w, s);
      s *= scale;
      ps[q][mm] = __expf(s - mfq) * ilq;
    }
    __syncthreads();
    const float* __restrict__ vb = vb0 + (size_t)m0 * JCOLS;
    for (int mm = 0; mm < TM; mm += 4) {
      float4 v0 = *(const float4*)(vb + (size_t)(mm + 0) * JCOLS);
      float4 v1 = *(const float4*)(vb + (size_t)(mm + 1) * JCOLS);
      float4 v2 = *(const float4*)(vb + (size_t)(mm + 2) * JCOLS);
      float4 v3 = *(const float4*)(vb + (size_t)(mm + 3) * JCOLS);
#pragma unroll
      for (int qq = 0; qq < TQ; ++qq) {
        float4 p = *(const float4*)&ps[qq][mm];
        acc[qq].x = fmaf(p.x, v0.x, acc[qq].x);
        acc[qq].y = fmaf(p.x, v0.y, acc[qq].y);
        acc[qq].z = fmaf(p.x, v0.z, acc[qq].z);
        acc[qq].w = fmaf(p.x, v0.w, acc[qq].w);
        acc[qq].x = fmaf(p.y, v1.x, acc[qq].x);
        acc[qq].y = fmaf(p.y, v1.y, acc[qq].y);
        acc[qq].z = fmaf(p.y, v1.z, acc[qq].z);
        acc[qq].w = fmaf(p.y, v1.w, acc[qq].w);
        acc[qq].x = fmaf(p.z, v2.x, acc[qq].x);
        acc[qq].y = fmaf(p.z, v2.y, acc[qq].y);
        acc[qq].z = fmaf(p.z, v2.z, acc[qq].z);
        acc[qq].w = fmaf(p.z, v2.w, acc[qq].w);
        acc[qq].x = fmaf(p.w, v3.x, acc[qq].x);
        acc[qq].y = fmaf(p.w, v3.y, acc[qq].y);
        acc[qq].z = fmaf(p.w, v3.z, acc[qq].z);
        acc[qq].w = fmaf(p.w, v3.w, acc[qq].w);
      }
    }
  }

#pragma unroll
  for (int qq = 0; qq < TQ; ++qq) {
    *(float4*)(out + (size_t)(nbase + q0 + qq) * DIM + tid * 4) = acc[qq];
  }
}

// ---------------------------------------------------------------------------
extern "C" void kernel_launch(void* const* d_in, const int* in_sizes, int n_in,
                              void* d_out, int out_size, void* d_ws,
                              size_t ws_size, hipStream_t stream) {
  const float* x = (const float*)d_in[0];
  const float* basis = (const float*)d_in[1];
  const float* Wq = (const float*)d_in[2];
  const float* bq = (const float*)d_in[3];
  const float* Wk = (const float*)d_in[4];
  const float* bk = (const float*)d_in[5];
  const float* Wv = (const float*)d_in[6];
  const float* bv = (const float*)d_in[7];
  float* out = (float*)d_out;
  float* ws = (float*)d_ws;
  float* Wcat = ws;
  float* bcat = ws + BCAT_OFF;
  float* Y = ws + Y_OFF;

  // Assemble Wcat = [Wv; basis@Wq; basis@Wk; 0] and bcat = [bv; cq; ck; 0].
  hipMemcpyAsync(Wcat, Wv, (size_t)DIM * DIM * sizeof(float),
                 hipMemcpyDeviceToDevice, stream);
  hipMemsetAsync(Wcat + (size_t)KAN_OFF * DIM, 0,
                 (size_t)(JCOLS - KAN_OFF) * DIM * sizeof(float), stream);
  hipMemcpyAsync(bcat, bv, DIM * sizeof(float), hipMemcpyDeviceToDevice,
                 stream);
  hipMemsetAsync(bcat + KAN_OFF, 0, (JCOLS - KAN_OFF) * sizeof(float), stream);
  k_basisW<<<dim3(2, DIM / 256, 8), 256, 0, stream>>>(basis, Wq, Wk, Wcat);
  k_basisB<<<dim3(32), 64, 0, stream>>>(basis, bq, bk, bcat);

  // Fused projection GEMM: Y[:, :1024]=v, [:,1024:1040]=kan_q, [:,1040:1056]=kan_k
  k_gemm<<<dim3(JCOLS / BN, NTOK / BM), 256, 0, stream>>>(x, Wcat, bcat, Y);

  // Attention
  k_attn<<<dim3(SEQ / TQ, BATCH), 256, 0, stream>>>(Y, out);
}

// Round 2
// 255.883 us; speedup vs baseline: 3.7240x; 3.7240x over previous
//
#include <hip/hip_runtime.h>
#include <math.h>

typedef unsigned short u16;
typedef __attribute__((ext_vector_type(8))) short short8;   // 8 bf16 = 4 VGPR
typedef __attribute__((ext_vector_type(4))) short short4v;  // 4 bf16 = 2 VGPR
typedef __attribute__((ext_vector_type(4))) float floatx4;  // MFMA C/D

#define DIM 1024
#define SEQ 2048
#define BATCH 4
#define NTOK 8192
#define NBROWS 1152   // GEMM N: 1024 v | 16 kanq | 16 kank | 96 pad (discarded)

// workspace layout (bytes)
#define OFF_XBF   0u
#define OFF_VT    16777216u
#define OFF_WB    33554432u
#define OFF_KANQ  35913728u
#define OFF_KANK  36438016u
#define OFF_WKAN  36962304u
#define OFF_BCAT  37093376u   // end = 37097984 (< 40.1MB used in round 1)

__device__ __forceinline__ u16 f2bf(float x) {
  union { float f; unsigned u; } v; v.f = x;
  unsigned r = v.u + 0x7fffu + ((v.u >> 16) & 1u);   // RNE
  return (u16)(r >> 16);
}

// ---------------------------------------------------------------------------
// fp32 -> bf16 cast, 8 elements/thread, grid sized exactly
// ---------------------------------------------------------------------------
__global__ __launch_bounds__(256) void k_cast(const float* __restrict__ in,
                                              u16* __restrict__ outp) {
  const int i = (blockIdx.x * 256 + threadIdx.x) * 8;
  float4 a = *(const float4*)(in + i);
  float4 b = *(const float4*)(in + i + 4);
  short8 o;
  o[0] = f2bf(a.x); o[1] = f2bf(a.y); o[2] = f2bf(a.z); o[3] = f2bf(a.w);
  o[4] = f2bf(b.x); o[5] = f2bf(b.y); o[6] = f2bf(b.z); o[7] = f2bf(b.w);
  *(short8*)(outp + i) = o;
}

// ---------------------------------------------------------------------------
// wkan[w*16+f][d] += sum_e basis[f][e] * W_w[e][d]  (fp32, atomic, pre-zeroed)
// ---------------------------------------------------------------------------
__global__ __launch_bounds__(256) void k_basisW(
    const float* __restrict__ basis, const float* __restrict__ Wq,
    const float* __restrict__ Wk, float* __restrict__ wkan) {
  const int w = blockIdx.x;
  const int d = blockIdx.y * 256 + threadIdx.x;
  const int e0 = blockIdx.z * 128;
  const float* __restrict__ W = w ? Wk : Wq;
  float acc[16];
#pragma unroll
  for (int f = 0; f < 16; ++f) acc[f] = 0.f;
#pragma unroll 4
  for (int e = e0; e < e0 + 128; ++e) {
    float wv = W[e * DIM + d];
#pragma unroll
    for (int f = 0; f < 16; ++f)
      acc[f] = fmaf(basis[f * DIM + e], wv, acc[f]);
  }
#pragma unroll
  for (int f = 0; f < 16; ++f)
    atomicAdd(&wkan[(size_t)(w * 16 + f) * DIM + d], acc[f]);
}

// ---------------------------------------------------------------------------
// bcat[1024 + w*16 + f] = sum_e basis[f][e] * b_w[e]
// ---------------------------------------------------------------------------
__global__ void k_basisB(const float* __restrict__ basis,
                         const float* __restrict__ bq,
                         const float* __restrict__ bk,
                         float* __restrict__ bcat) {
  const int w = blockIdx.x >> 4, f = blockIdx.x & 15;
  const float* __restrict__ bb = w ? bk : bq;
  const int lane = threadIdx.x;
  float acc = 0.f;
#pragma unroll
  for (int j = 0; j < DIM / 64; ++j) {
    int e = lane + 64 * j;
    acc = fmaf(basis[f * DIM + e], bb[e], acc);
  }
#pragma unroll
  for (int off = 32; off; off >>= 1) acc += __shfl_down(acc, off, 64);
  if (lane == 0) bcat[1024 + w * 16 + f] = acc;
}

// ---------------------------------------------------------------------------
// m97-style bf16 MFMA GEMM: C[n][j] = x_bf[n][:] . wb[j][:] + bcat[j]
// 128x128 tile, BK=64, 256 thr, global_load_lds width 16.
// Epilogue: j<1024 -> Vt[b][j][m] bf16 (transposed); 1024..1039 -> kanq
// (x softmax-scale 1/32); 1040..1055 -> kank; >=1056 -> discard.
// grid (9, 64)
// ---------------------------------------------------------------------------
__device__ __forceinline__ void gll16(const void* g, void* s) {
  __builtin_amdgcn_global_load_lds(
      (const __attribute__((address_space(1))) void*)g,
      (__attribute__((address_space(3))) void*)s, 16, 0, 0);
}

__global__ __launch_bounds__(256) void k_gemm(
    const u16* __restrict__ A, const u16* __restrict__ B,
    const float* __restrict__ bc, u16* __restrict__ vt,
    u16* __restrict__ kanq, u16* __restrict__ kank) {
  __shared__ u16 As[128 * 64];
  __shared__ u16 Bs[128 * 64];
  const int jb = blockIdx.x, nb = blockIdx.y;
  const int tid = threadIdx.x;
  const int w = tid >> 6, l = tid & 63;
  const int wr = w >> 1, wc = w & 1;
  const int lq = l & 15, quad = l >> 4;
  const int srow = l >> 3, scol = (l & 7) * 8;
  const u16* Ab = A + (size_t)(nb * 128 + w * 8 + srow) * DIM + scol;
  const u16* Bb = B + (size_t)(jb * 128 + w * 8 + srow) * DIM + scol;
  floatx4 acc[4][4];
  const floatx4 z4 = {0.f, 0.f, 0.f, 0.f};
#pragma unroll
  for (int i = 0; i < 4; ++i)
#pragma unroll
    for (int j = 0; j < 4; ++j) acc[i][j] = z4;

  for (int k0 = 0; k0 < DIM; k0 += 64) {
    __syncthreads();
#pragma unroll
    for (int i = 0; i < 4; ++i) {
      gll16(Ab + (size_t)i * 32 * DIM + k0, &As[(i * 32 + w * 8) * 64]);
      gll16(Bb + (size_t)i * 32 * DIM + k0, &Bs[(i * 32 + w * 8) * 64]);
    }
    __syncthreads();
#pragma unroll
    for (int kk = 0; kk < 64; kk += 32) {
      short8 af[4], bf[4];
#pragma unroll
      for (int t = 0; t < 4; ++t)
        af[t] = *(const short8*)&As[(wr * 64 + t * 16 + lq) * 64 + kk + quad * 8];
#pragma unroll
      for (int t = 0; t < 4; ++t)
        bf[t] = *(const short8*)&Bs[(wc * 64 + t * 16 + lq) * 64 + kk + quad * 8];
#pragma unroll
      for (int rt = 0; rt < 4; ++rt)
#pragma unroll
        for (int ct = 0; ct < 4; ++ct)
          acc[rt][ct] = __builtin_amdgcn_mfma_f32_16x16x32_bf16(
              af[rt], bf[ct], acc[rt][ct], 0, 0, 0);
    }
  }

  const int bt = nb >> 4;  // batch (128-row blocks never straddle: 2048/128=16)
  const size_t vtB = (size_t)bt * DIM * SEQ;
#pragma unroll
  for (int ct = 0; ct < 4; ++ct) {
    const int jbase = jb * 128 + wc * 64 + ct * 16;
    if (jbase >= 1056) continue;
    const int j = jbase + lq;
    const float bias = bc[j];
#pragma unroll
    for (int rt = 0; rt < 4; ++rt) {
      const int t0 = nb * 128 + wr * 64 + rt * 16 + quad * 4;
      if (jbase < 1024) {
        short4v pk;
        pk[0] = (short)f2bf(acc[rt][ct][0] + bias);
        pk[1] = (short)f2bf(acc[rt][ct][1] + bias);
        pk[2] = (short)f2bf(acc[rt][ct][2] + bias);
        pk[3] = (short)f2bf(acc[rt][ct][3] + bias);
        const int mloc = t0 & (SEQ - 1);
        *(short4v*)(vt + vtB + (size_t)j * SEQ + mloc) = pk;
      } else if (jbase < 1040) {
        const int f = j - 1024;
#pragma unroll
        for (int r = 0; r < 4; ++r)
          kanq[(size_t)(t0 + r) * 32 + f] =
              f2bf((acc[rt][ct][r] + bias) * 0.03125f);
      } else {
        const int f = j - 1040;
#pragma unroll
        for (int r = 0; r < 4; ++r)
          kank[(size_t)(t0 + r) * 32 + f] = f2bf(acc[rt][ct][r] + bias);
      }
    }
  }
}

// ---------------------------------------------------------------------------
// Single-pass fused attention (no max-subtract: |s| <~ 0.5 guaranteed).
// Block: 64 q-rows x 128 d-cols of one batch; 4 waves.
// Per 32-m chunk: wave w scores q-tile w (2 MFMA) -> P=exp(s) bf16 -> LDS;
// stage Vt chunk (padded LDS); all waves PV (8 MFMA, wave owns 32 d).
// L = sum exp accumulated in regs; final out = O/L.
// grid 1024 linear; idx%32 = (b,dslice) so V-sharers land on same XCD.
// ---------------------------------------------------------------------------
#define PVT 40  // LDS row stride (u16): 80B, 16B-aligned, conflict-free-ish

__global__ __launch_bounds__(256) void k_pv(const u16* __restrict__ vt,
                                            const u16* __restrict__ kanq,
                                            const u16* __restrict__ kank,
                                            float* __restrict__ out) {
  __shared__ u16 Vs[128 * PVT];
  __shared__ u16 Ps[64 * PVT];
  __shared__ float Ls[64];
  const int idx = blockIdx.x;
  const int qb = idx >> 5;
  const int g = idx & 31;
  const int b = g >> 3, ds = g & 7;
  const int q0 = qb * 64, d0 = ds * 128;
  const int tid = threadIdx.x, w = tid >> 6, l = tid & 63;
  const int lq = l & 15, quad = l >> 4;
  const u16* kq = kanq + (size_t)b * SEQ * 32;
  const u16* kk = kank + (size_t)b * SEQ * 32;
  const u16* vtb = vt + (size_t)b * DIM * SEQ + (size_t)d0 * SEQ;
  const short8 aq =
      *(const short8*)(kq + (size_t)(q0 + w * 16 + lq) * 32 + quad * 8);
  const floatx4 z4 = {0.f, 0.f, 0.f, 0.f};
  floatx4 accO[4][2];
#pragma unroll
  for (int i = 0; i < 4; ++i) { accO[i][0] = z4; accO[i][1] = z4; }
  float lac[4] = {0.f, 0.f, 0.f, 0.f};
  const int r0 = tid >> 2, r1 = (256 + tid) >> 2;
  const int seg = (tid & 3) * 8;

  for (int m0 = 0; m0 < SEQ; m0 += 32) {
    short8 s0v = *(const short8*)(vtb + (size_t)r0 * SEQ + m0 + seg);
    short8 s1v = *(const short8*)(vtb + (size_t)r1 * SEQ + m0 + seg);
    short8 bq0 = *(const short8*)(kk + (size_t)(m0 + lq) * 32 + quad * 8);
    short8 bq1 = *(const short8*)(kk + (size_t)(m0 + 16 + lq) * 32 + quad * 8);
    floatx4 sc0 = __builtin_amdgcn_mfma_f32_16x16x32_bf16(aq, bq0, z4, 0, 0, 0);
    floatx4 sc1 = __builtin_amdgcn_mfma_f32_16x16x32_bf16(aq, bq1, z4, 0, 0, 0);
    u16 p0[4], p1[4];
#pragma unroll
    for (int r = 0; r < 4; ++r) {
      float e0 = __expf(sc0[r]);
      float e1 = __expf(sc1[r]);
      lac[r] += e0 + e1;
      p0[r] = f2bf(e0);
      p1[r] = f2bf(e1);
    }
    *(short8*)&Vs[r0 * PVT + seg] = s0v;
    *(short8*)&Vs[r1 * PVT + seg] = s1v;
#pragma unroll
    for (int r = 0; r < 4; ++r) {
      Ps[(w * 16 + quad * 4 + r) * PVT + lq] = p0[r];
      Ps[(w * 16 + quad * 4 + r) * PVT + 16 + lq] = p1[r];
    }
    __syncthreads();
    short8 pf[4], vf[2];
#pragma unroll
    for (int qt = 0; qt < 4; ++qt)
      pf[qt] = *(const short8*)&Ps[(qt * 16 + lq) * PVT + quad * 8];
#pragma unroll
    for (int dt = 0; dt < 2; ++dt)
      vf[dt] = *(const short8*)&Vs[(w * 32 + dt * 16 + lq) * PVT + quad * 8];
#pragma unroll
    for (int qt = 0; qt < 4; ++qt)
#pragma unroll
      for (int dt = 0; dt < 2; ++dt)
        accO[qt][dt] = __builtin_amdgcn_mfma_f32_16x16x32_bf16(
            pf[qt], vf[dt], accO[qt][dt], 0, 0, 0);
    __syncthreads();
  }

#pragma unroll
  for (int r = 0; r < 4; ++r) {
    float v = lac[r];
    v += __shfl_xor(v, 1, 64);
    v += __shfl_xor(v, 2, 64);
    v += __shfl_xor(v, 4, 64);
    v += __shfl_xor(v, 8, 64);
    if (lq == 0) Ls[w * 16 + quad * 4 + r] = v;
  }
  __syncthreads();
  float* ob = out + (size_t)b * SEQ * DIM + (size_t)q0 * DIM;
#pragma unroll
  for (int qt = 0; qt < 4; ++qt) {
    float rinv[4];
#pragma unroll
    for (int r = 0; r < 4; ++r) rinv[r] = 1.f / Ls[qt * 16 + quad * 4 + r];
#pragma unroll
    for (int dt = 0; dt < 2; ++dt) {
      const int d = d0 + w * 32 + dt * 16 + lq;
#pragma unroll
      for (int r = 0; r < 4; ++r)
        ob[(size_t)(qt * 16 + quad * 4 + r) * DIM + d] =
            accO[qt][dt][r] * rinv[r];
    }
  }
}

// ---------------------------------------------------------------------------
extern "C" void kernel_launch(void* const* d_in, const int* in_sizes, int n_in,
                              void* d_out, int out_size, void* d_ws,
                              size_t ws_size, hipStream_t stream) {
  const float* x = (const float*)d_in[0];
  const float* basis = (const float*)d_in[1];
  const float* Wq = (const float*)d_in[2];
  const float* bq = (const float*)d_in[3];
  const float* Wk = (const float*)d_in[4];
  const float* bk = (const float*)d_in[5];
  const float* Wv = (const float*)d_in[6];
  const float* bv = (const float*)d_in[7];
  float* out = (float*)d_out;
  char* w8 = (char*)d_ws;
  u16* xbf = (u16*)(w8 + OFF_XBF);
  u16* vt = (u16*)(w8 + OFF_VT);
  u16* wb = (u16*)(w8 + OFF_WB);
  u16* kanq = (u16*)(w8 + OFF_KANQ);
  u16* kank = (u16*)(w8 + OFF_KANK);
  float* wkan = (float*)(w8 + OFF_WKAN);
  float* bcat = (float*)(w8 + OFF_BCAT);

  hipMemsetAsync(wkan, 0, 32 * DIM * sizeof(float), stream);
  hipMemsetAsync(kanq, 0, (size_t)NTOK * 32 * sizeof(u16), stream);
  hipMemsetAsync(kank, 0, (size_t)NTOK * 32 * sizeof(u16), stream);
  hipMemsetAsync(bcat, 0, NBROWS * sizeof(float), stream);
  hipMemcpyAsync(bcat, bv, DIM * sizeof(float), hipMemcpyDeviceToDevice,
                 stream);

  k_basisW<<<dim3(2, 4, 8), 256, 0, stream>>>(basis, Wq, Wk, wkan);
  k_basisB<<<32, 64, 0, stream>>>(basis, bq, bk, bcat);
  k_cast<<<4096, 256, 0, stream>>>(x, xbf);                    // 8192x1024
  k_cast<<<512, 256, 0, stream>>>(Wv, wb);                     // rows 0..1023
  k_cast<<<16, 256, 0, stream>>>(wkan, wb + 1024 * 1024);      // rows 1024..1055

  k_gemm<<<dim3(9, 64), 256, 0, stream>>>(xbf, wb, bcat, vt, kanq, kank);
  k_pv<<<1024, 256, 0, stream>>>(vt, kanq, kank, out);
}

// Round 3
// 238.933 us; speedup vs baseline: 3.9882x; 1.0709x over previous
//
#include <hip/hip_runtime.h>
#include <math.h>

typedef unsigned short u16;
typedef __attribute__((ext_vector_type(8))) short short8;    // 8 bf16 = 4 VGPR
typedef __attribute__((ext_vector_type(4))) short short4v;   // 4 bf16 = 2 VGPR
typedef __attribute__((ext_vector_type(4))) float floatx4;   // 16x16 MFMA C/D
typedef __attribute__((ext_vector_type(16))) float floatx16; // 32x32 MFMA C/D

#define DIM 1024
#define SEQ 2048
#define BATCH 4
#define NTOK 8192
#define NBROWS 1152   // GEMM N: 1024 v | 16 kanq | 16 kank | 96 pad (discarded)

// workspace layout (bytes)
#define OFF_XBF   0u
#define OFF_VT    16777216u
#define OFF_WB    33554432u
#define OFF_KANQ  35913728u   // 8192 x 16 bf16 = 256 KB
#define OFF_KANK  36438016u   // 8192 x 16 bf16 = 256 KB
#define OFF_WKAN  36962304u
#define OFF_BCAT  37093376u

__device__ __forceinline__ u16 f2bf(float x) {
  union { float f; unsigned u; } v; v.f = x;
  unsigned r = v.u + 0x7fffu + ((v.u >> 16) & 1u);   // RNE
  return (u16)(r >> 16);
}

// ---------------------------------------------------------------------------
// fp32 -> bf16 cast, 8 elements/thread
// ---------------------------------------------------------------------------
__global__ __launch_bounds__(256) void k_cast(const float* __restrict__ in,
                                              u16* __restrict__ outp) {
  const int i = (blockIdx.x * 256 + threadIdx.x) * 8;
  float4 a = *(const float4*)(in + i);
  float4 b = *(const float4*)(in + i + 4);
  short8 o;
  o[0] = f2bf(a.x); o[1] = f2bf(a.y); o[2] = f2bf(a.z); o[3] = f2bf(a.w);
  o[4] = f2bf(b.x); o[5] = f2bf(b.y); o[6] = f2bf(b.z); o[7] = f2bf(b.w);
  *(short8*)(outp + i) = o;
}

// ---------------------------------------------------------------------------
// wkan[w*16+f][d] += sum_e basis[f][e] * W_w[e][d]  (fp32, atomic, pre-zeroed)
// ---------------------------------------------------------------------------
__global__ __launch_bounds__(256) void k_basisW(
    const float* __restrict__ basis, const float* __restrict__ Wq,
    const float* __restrict__ Wk, float* __restrict__ wkan) {
  const int w = blockIdx.x;
  const int d = blockIdx.y * 256 + threadIdx.x;
  const int e0 = blockIdx.z * 128;
  const float* __restrict__ W = w ? Wk : Wq;
  float acc[16];
#pragma unroll
  for (int f = 0; f < 16; ++f) acc[f] = 0.f;
#pragma unroll 4
  for (int e = e0; e < e0 + 128; ++e) {
    float wv = W[e * DIM + d];
#pragma unroll
    for (int f = 0; f < 16; ++f)
      acc[f] = fmaf(basis[f * DIM + e], wv, acc[f]);
  }
#pragma unroll
  for (int f = 0; f < 16; ++f)
    atomicAdd(&wkan[(size_t)(w * 16 + f) * DIM + d], acc[f]);
}

// ---------------------------------------------------------------------------
// bcat[1024 + w*16 + f] = sum_e basis[f][e] * b_w[e]
// ---------------------------------------------------------------------------
__global__ void k_basisB(const float* __restrict__ basis,
                         const float* __restrict__ bq,
                         const float* __restrict__ bk,
                         float* __restrict__ bcat) {
  const int w = blockIdx.x >> 4, f = blockIdx.x & 15;
  const float* __restrict__ bb = w ? bk : bq;
  const int lane = threadIdx.x;
  float acc = 0.f;
#pragma unroll
  for (int j = 0; j < DIM / 64; ++j) {
    int e = lane + 64 * j;
    acc = fmaf(basis[f * DIM + e], bb[e], acc);
  }
#pragma unroll
  for (int off = 32; off; off >>= 1) acc += __shfl_down(acc, off, 64);
  if (lane == 0) bcat[1024 + w * 16 + f] = acc;
}

// ---------------------------------------------------------------------------
// m97-style bf16 MFMA GEMM (unchanged structure); epilogue: V transposed,
// kanq (x 1/32) / kank stored 16-wide (no pad; K=16 score MFMA needs none).
// ---------------------------------------------------------------------------
__device__ __forceinline__ void gll16(const void* g, void* s) {
  __builtin_amdgcn_global_load_lds(
      (const __attribute__((address_space(1))) void*)g,
      (__attribute__((address_space(3))) void*)s, 16, 0, 0);
}

__global__ __launch_bounds__(256) void k_gemm(
    const u16* __restrict__ A, const u16* __restrict__ B,
    const float* __restrict__ bc, u16* __restrict__ vt,
    u16* __restrict__ kanq, u16* __restrict__ kank) {
  __shared__ u16 As[128 * 64];
  __shared__ u16 Bs[128 * 64];
  const int jb = blockIdx.x, nb = blockIdx.y;
  const int tid = threadIdx.x;
  const int w = tid >> 6, l = tid & 63;
  const int wr = w >> 1, wc = w & 1;
  const int lq = l & 15, quad = l >> 4;
  const int srow = l >> 3, scol = (l & 7) * 8;
  const u16* Ab = A + (size_t)(nb * 128 + w * 8 + srow) * DIM + scol;
  const u16* Bb = B + (size_t)(jb * 128 + w * 8 + srow) * DIM + scol;
  floatx4 acc[4][4];
  const floatx4 z4 = {0.f, 0.f, 0.f, 0.f};
#pragma unroll
  for (int i = 0; i < 4; ++i)
#pragma unroll
    for (int j = 0; j < 4; ++j) acc[i][j] = z4;

  for (int k0 = 0; k0 < DIM; k0 += 64) {
    __syncthreads();
#pragma unroll
    for (int i = 0; i < 4; ++i) {
      gll16(Ab + (size_t)i * 32 * DIM + k0, &As[(i * 32 + w * 8) * 64]);
      gll16(Bb + (size_t)i * 32 * DIM + k0, &Bs[(i * 32 + w * 8) * 64]);
    }
    __syncthreads();
#pragma unroll
    for (int kk = 0; kk < 64; kk += 32) {
      short8 af[4], bf[4];
#pragma unroll
      for (int t = 0; t < 4; ++t)
        af[t] = *(const short8*)&As[(wr * 64 + t * 16 + lq) * 64 + kk + quad * 8];
#pragma unroll
      for (int t = 0; t < 4; ++t)
        bf[t] = *(const short8*)&Bs[(wc * 64 + t * 16 + lq) * 64 + kk + quad * 8];
#pragma unroll
      for (int rt = 0; rt < 4; ++rt)
#pragma unroll
        for (int ct = 0; ct < 4; ++ct)
          acc[rt][ct] = __builtin_amdgcn_mfma_f32_16x16x32_bf16(
              af[rt], bf[ct], acc[rt][ct], 0, 0, 0);
    }
  }

  const int bt = nb >> 4;  // batch (128-row blocks never straddle)
  const size_t vtB = (size_t)bt * DIM * SEQ;
#pragma unroll
  for (int ct = 0; ct < 4; ++ct) {
    const int jbase = jb * 128 + wc * 64 + ct * 16;
    if (jbase >= 1056) continue;
    const int j = jbase + lq;
    const float bias = bc[j];
#pragma unroll
    for (int rt = 0; rt < 4; ++rt) {
      const int t0 = nb * 128 + wr * 64 + rt * 16 + quad * 4;
      if (jbase < 1024) {
        short4v pk;
        pk[0] = (short)f2bf(acc[rt][ct][0] + bias);
        pk[1] = (short)f2bf(acc[rt][ct][1] + bias);
        pk[2] = (short)f2bf(acc[rt][ct][2] + bias);
        pk[3] = (short)f2bf(acc[rt][ct][3] + bias);
        const int mloc = t0 & (SEQ - 1);
        *(short4v*)(vt + vtB + (size_t)j * SEQ + mloc) = pk;
      } else if (jbase < 1040) {
        const int f = j - 1024;
#pragma unroll
        for (int r = 0; r < 4; ++r)
          kanq[(size_t)(t0 + r) * 16 + f] =
              f2bf((acc[rt][ct][r] + bias) * 0.03125f);
      } else {
        const int f = j - 1040;
#pragma unroll
        for (int r = 0; r < 4; ++r)
          kank[(size_t)(t0 + r) * 16 + f] = f2bf(acc[rt][ct][r] + bias);
      }
    }
  }
}

// ---------------------------------------------------------------------------
// k_pv v3: single-pass attention, 32x32 MFMA, P never touches LDS.
// Block = 128q x 128d of one batch, 4 waves, wave = 32q x 128d.
// Per 32-m chunk / wave:
//   S^T = mfma_32x32x16(A=kank[32m x 16f], B=kanq[32q x 16f])  (K=16 exact)
//   P-frags: p1[jj]=exp(sc[jj]), p2[jj]=exp(sc[8+jj]) -- C-layout == valid
//   B-fragment under permuted k<->m bijection (p=h*8+jj -> m=4h+jj | 8+4h+jj-4)
//   O^T += mfma_32x32x16(A=V^T frag [d x m-perm], B=P-frag)   x 4 d-tiles x 2
// V staged in LDS (72B row stride: 2-way conflicts = free), reg-double-buffered,
// ONE barrier per chunk. L = running sum of exp, shfl_xor(32) at end.
// grid 512: bx>>5 = q-block, bx&31 = (b,ds) -> V-slice sharers on same XCD.
// ---------------------------------------------------------------------------
#define VSTRIDE 36  // u16 per Vs row = 72 B

__global__ __launch_bounds__(256) void k_pv(const u16* __restrict__ vt,
                                            const u16* __restrict__ kanq,
                                            const u16* __restrict__ kank,
                                            float* __restrict__ out) {
  __shared__ u16 Vs[2][128 * VSTRIDE];
  const int bx = blockIdx.x;
  const int qb = bx >> 5;
  const int g = bx & 31;
  const int b = g >> 3, ds = g & 7;
  const int q0 = qb * 128, d0 = ds * 128;
  const int tid = threadIdx.x, w = tid >> 6, l = tid & 63;
  const int lq = l & 31, h = l >> 5;
  const u16* kq = kanq + (size_t)b * SEQ * 16;
  const u16* kk = kank + (size_t)b * SEQ * 16;
  const u16* vtb = vt + ((size_t)b * DIM + d0) * SEQ;

  // score B-fragment: kanq row (q0 + w*32 + lq), f = h*8..h*8+7  (persistent)
  const short8 bq =
      *(const short8*)(kq + (size_t)(q0 + w * 32 + lq) * 16 + h * 8);

  // staging: thread covers 32B of one d-row per chunk
  const int srow = tid >> 1, shalf = tid & 1;
  const u16* sgp = vtb + (size_t)srow * SEQ + shalf * 16;
  const int slo = srow * VSTRIDE + shalf * 16;  // u16 index in a buffer

  const floatx16 z16 = {0.f,0.f,0.f,0.f,0.f,0.f,0.f,0.f,
                        0.f,0.f,0.f,0.f,0.f,0.f,0.f,0.f};
  floatx16 accO[4];
#pragma unroll
  for (int dt = 0; dt < 4; ++dt) accO[dt] = z16;
  float lac = 0.f;

  // prologue: stage chunk 0 into buf 0; prefetch kank frag for chunk 0
  {
    short8 v0 = *(const short8*)(sgp);
    short8 v1 = *(const short8*)(sgp + 8);
    *(short4v*)&Vs[0][slo + 0] = __builtin_shufflevector(v0, v0, 0, 1, 2, 3);
    *(short4v*)&Vs[0][slo + 4] = __builtin_shufflevector(v0, v0, 4, 5, 6, 7);
    *(short4v*)&Vs[0][slo + 8] = __builtin_shufflevector(v1, v1, 0, 1, 2, 3);
    *(short4v*)&Vs[0][slo + 12] = __builtin_shufflevector(v1, v1, 4, 5, 6, 7);
  }
  short8 kkn = *(const short8*)(kk + (size_t)lq * 16 + h * 8);
  __syncthreads();

  for (int it = 0; it < SEQ / 32; ++it) {
    const int mn = (it + 1 < SEQ / 32) ? (it + 1) * 32 : 0;
    // prefetch next V chunk + next kank fragment (consumed after compute)
    short8 nv0 = *(const short8*)(sgp + mn);
    short8 nv1 = *(const short8*)(sgp + mn + 8);
    const short8 kkc = kkn;
    kkn = *(const short8*)(kk + (size_t)(mn + lq) * 16 + h * 8);

    // scores S^T (32m x 32q), K = 16 (exact f width)
    floatx16 sc =
        __builtin_amdgcn_mfma_f32_32x32x16_bf16(kkc, bq, z16, 0, 0, 0);

    short8 p1, p2;
    float ls = 0.f;
#pragma unroll
    for (int i = 0; i < 8; ++i) {
      float e = __expf(sc[i]);
      ls += e;
      p1[i] = (short)f2bf(e);
    }
#pragma unroll
    for (int i = 0; i < 8; ++i) {
      float e = __expf(sc[8 + i]);
      ls += e;
      p2[i] = (short)f2bf(e);
    }
    lac += ls;

    // PV: O^T[d][q] += V-frag * P-frag, 4 d-tiles, 2 m-halves
    const u16* vb = &Vs[it & 1][0];
#pragma unroll
    for (int dt = 0; dt < 4; ++dt) {
      const int r = (dt * 32 + lq) * VSTRIDE + h * 4;
      short4v x0 = *(const short4v*)(vb + r);        // m = 4h..4h+3
      short4v x1 = *(const short4v*)(vb + r + 8);    // m = 8+4h..
      short4v x2 = *(const short4v*)(vb + r + 16);   // m = 16+4h..
      short4v x3 = *(const short4v*)(vb + r + 24);   // m = 24+4h..
      short8 a1 = __builtin_shufflevector(x0, x1, 0, 1, 2, 3, 4, 5, 6, 7);
      short8 a2 = __builtin_shufflevector(x2, x3, 0, 1, 2, 3, 4, 5, 6, 7);
      accO[dt] =
          __builtin_amdgcn_mfma_f32_32x32x16_bf16(a1, p1, accO[dt], 0, 0, 0);
      accO[dt] =
          __builtin_amdgcn_mfma_f32_32x32x16_bf16(a2, p2, accO[dt], 0, 0, 0);
    }

    // write next chunk into other buffer, single barrier
    u16* sl = &Vs[(it + 1) & 1][0];
    *(short4v*)&sl[slo + 0] = __builtin_shufflevector(nv0, nv0, 0, 1, 2, 3);
    *(short4v*)&sl[slo + 4] = __builtin_shufflevector(nv0, nv0, 4, 5, 6, 7);
    *(short4v*)&sl[slo + 8] = __builtin_shufflevector(nv1, nv1, 0, 1, 2, 3);
    *(short4v*)&sl[slo + 12] = __builtin_shufflevector(nv1, nv1, 4, 5, 6, 7);
    __syncthreads();
  }

  // finalize: L[q] = lac + partner half; divide; store O (fp32)
  lac += __shfl_xor(lac, 32, 64);
  const float rinv = 1.f / lac;
  float* ob = out + ((size_t)b * SEQ + q0 + w * 32 + lq) * DIM + d0;
#pragma unroll
  for (int dt = 0; dt < 4; ++dt) {
#pragma unroll
    for (int gi = 0; gi < 4; ++gi) {
      float4 o;
      o.x = accO[dt][gi * 4 + 0] * rinv;
      o.y = accO[dt][gi * 4 + 1] * rinv;
      o.z = accO[dt][gi * 4 + 2] * rinv;
      o.w = accO[dt][gi * 4 + 3] * rinv;
      *(float4*)(ob + dt * 32 + gi * 8 + h * 4) = o;
    }
  }
}

// ---------------------------------------------------------------------------
extern "C" void kernel_launch(void* const* d_in, const int* in_sizes, int n_in,
                              void* d_out, int out_size, void* d_ws,
                              size_t ws_size, hipStream_t stream) {
  const float* x = (const float*)d_in[0];
  const float* basis = (const float*)d_in[1];
  const float* Wq = (const float*)d_in[2];
  const float* bq = (const float*)d_in[3];
  const float* Wk = (const float*)d_in[4];
  const float* bk = (const float*)d_in[5];
  const float* Wv = (const float*)d_in[6];
  const float* bv = (const float*)d_in[7];
  float* out = (float*)d_out;
  char* w8 = (char*)d_ws;
  u16* xbf = (u16*)(w8 + OFF_XBF);
  u16* vt = (u16*)(w8 + OFF_VT);
  u16* wb = (u16*)(w8 + OFF_WB);
  u16* kanq = (u16*)(w8 + OFF_KANQ);
  u16* kank = (u16*)(w8 + OFF_KANK);
  float* wkan = (float*)(w8 + OFF_WKAN);
  float* bcat = (float*)(w8 + OFF_BCAT);

  hipMemsetAsync(wkan, 0, 32 * DIM * sizeof(float), stream);
  hipMemsetAsync(bcat, 0, NBROWS * sizeof(float), stream);
  hipMemcpyAsync(bcat, bv, DIM * sizeof(float), hipMemcpyDeviceToDevice,
                 stream);

  k_basisW<<<dim3(2, 4, 8), 256, 0, stream>>>(basis, Wq, Wk, wkan);
  k_basisB<<<32, 64, 0, stream>>>(basis, bq, bk, bcat);
  k_cast<<<4096, 256, 0, stream>>>(x, xbf);                 // 8192x1024
  k_cast<<<512, 256, 0, stream>>>(Wv, wb);                  // rows 0..1023
  k_cast<<<16, 256, 0, stream>>>(wkan, wb + 1024 * 1024);   // rows 1024..1055

  k_gemm<<<dim3(9, 64), 256, 0, stream>>>(xbf, wb, bcat, vt, kanq, kank);
  k_pv<<<512, 256, 0, stream>>>(vt, kanq, kank, out);
}